// Round 2
// baseline (419.314 us; speedup 1.0000x reference)
//
#include <hip/hip_runtime.h>

constexpr int NQ = 512;
constexpr int NKV = 512;
constexpr int Hh = 16;
constexpr int Dd = 256;

// C = A @ W^T + bias. M=4096, N=256, K=256. BM=BN=64, BK=64.
// Next K-tile reg-prefetched after the publish barrier (1 block/CU -> no
// cross-block cover; in-block pipelining is the only latency hiding).
__global__ __launch_bounds__(256) void gemm_bias(
    const float* __restrict__ A, const float* __restrict__ W,
    const float* __restrict__ bias, float* __restrict__ C) {
  __shared__ float As[64][68];
  __shared__ float Ws[64][68];
  const int t = threadIdx.x;
  const int tx = t & 15, ty = t >> 4;
  const int m0 = blockIdx.x * 64, n0 = blockIdx.y * 64;

  float acc[4][4] = {};
  float4 av[4], wv[4];

#pragma unroll
  for (int i = 0; i < 4; ++i) {
    const int flat = i * 256 + t;
    const int r = flat >> 4, c4 = (flat & 15) << 2;
    av[i] = *(const float4*)(A + (size_t)(m0 + r) * 256 + c4);
    wv[i] = *(const float4*)(W + (size_t)(n0 + r) * 256 + c4);
  }

  for (int kb = 0; kb < 4; ++kb) {
#pragma unroll
    for (int i = 0; i < 4; ++i) {
      const int flat = i * 256 + t;
      const int r = flat >> 4, c4 = (flat & 15) << 2;
      As[c4 + 0][r] = av[i].x; As[c4 + 1][r] = av[i].y;
      As[c4 + 2][r] = av[i].z; As[c4 + 3][r] = av[i].w;
      Ws[c4 + 0][r] = wv[i].x; Ws[c4 + 1][r] = wv[i].y;
      Ws[c4 + 2][r] = wv[i].z; Ws[c4 + 3][r] = wv[i].w;
    }
    __syncthreads();
    if (kb < 3) {
#pragma unroll
      for (int i = 0; i < 4; ++i) {
        const int flat = i * 256 + t;
        const int r = flat >> 4, c4 = (flat & 15) << 2;
        av[i] = *(const float4*)(A + (size_t)(m0 + r) * 256 + (kb + 1) * 64 + c4);
        wv[i] = *(const float4*)(W + (size_t)(n0 + r) * 256 + (kb + 1) * 64 + c4);
      }
    }
#pragma unroll 16
    for (int k = 0; k < 64; ++k) {
      float a_[4], w_[4];
      *(float4*)a_ = *(const float4*)&As[k][ty << 2];
      *(float4*)w_ = *(const float4*)&Ws[k][tx << 2];
#pragma unroll
      for (int i = 0; i < 4; ++i)
#pragma unroll
        for (int j = 0; j < 4; ++j)
          acc[i][j] = fmaf(a_[i], w_[j], acc[i][j]);
    }
    if (kb < 3) __syncthreads();
  }

  const float4 bv = *(const float4*)(bias + n0 + (tx << 2));
  const float bb[4] = {bv.x, bv.y, bv.z, bv.w};
#pragma unroll
  for (int i = 0; i < 4; ++i) {
    float4 cv;
    cv.x = acc[i][0] + bb[0]; cv.y = acc[i][1] + bb[1];
    cv.z = acc[i][2] + bb[2]; cv.w = acc[i][3] + bb[3];
    *(float4*)(C + (size_t)(m0 + (ty << 2) + i) * 256 + n0 + (tx << 2)) = cv;
  }
}

// Fused masked softmax + per-head aggregation + L2 rescale.
// v3 structure: NO LDS for P (each wave's FMA slice of proj is exactly a
// coalesced 1KB global load -> L2-resident, loaded straight to registers).
// E is double-buffered in LDS -> ONE raw s_barrier per round with only
// lgkmcnt(0) published (global prefetches stay in flight across barriers).
// Race audit: E writes buf[rd&1] pre-barrier(rd); readers run between
// barrier(rd) and barrier(rd+1); next writer of that buf is after
// barrier(rd+1). RAW + WAR each separated by one barrier.
__global__ __launch_bounds__(512, 4) void attn_fused(
    const float* __restrict__ msg, const int* __restrict__ adj,
    const float* __restrict__ proj, float* __restrict__ attn_out) {
  __shared__ float Esh[2][4][8][16][12];  // 48 KB: [buf][oct][q][h^q][k(8 used)]

  const int t    = threadIdx.x;
  const int lane = t & 63;
  const int w    = t >> 6;      // wave 0..7
  const int oct  = w >> 1;      // k-quarter for FMA
  const int qh   = w & 1;       // q-half for FMA
  const int h    = lane >> 2;
  const int d4   = lane & 3;
  const int col  = lane << 2;   // = h*16 + d4*4
  const int q0   = blockIdx.x * 8;
  const int b    = blockIdx.y;

  // E-production decomposition
  const int p_h4  = t & 3;
  const int p_q   = (t >> 2) & 7;
  const int p_oct = (t >> 5) & 3;
  const int p_jp  = t >> 7;     // 0..3 (k-pair)

  const float* mrow = msg + ((size_t)(b * NQ + q0 + p_q) * NKV) * Hh + p_h4 * 4;
  const int*   arow = adj + (size_t)(b * NQ + q0 + p_q) * NKV;
  const float* pb   = proj + (size_t)b * NKV * Dd;

  float4 o[4] = {};
  float s[4] = {}, r[4] = {};

  float4 mA0, mA1, mB0, mB1;
  int2 aA, aB;
  {  // prologue: round-0 messages
    const int kg = p_oct * 128 + p_jp * 2;
    mA0 = *(const float4*)(mrow + (size_t)kg * Hh);
    mA1 = *(const float4*)(mrow + (size_t)(kg + 1) * Hh);
    aA = *(const int2*)(arow + kg);
  }

#define ATTN_ROUND(RD, BUF, MC0, MC1, AC, MN0, MN1, AN)                        \
  {                                                                            \
    /* P straight to registers: coalesced 1KB loads, L2-hit; issued first   */ \
    /* so E-compute + barrier wait covers the latency.                      */ \
    float4 p4[8];                                                              \
    _Pragma("unroll")                                                          \
    for (int j = 0; j < 8; ++j)                                                \
      p4[j] = *(const float4*)(pb + (size_t)(oct * 128 + (RD) * 8 + j) * Dd + col); \
    {                                                                          \
      float e0[4], e1[4];                                                      \
      e0[0] = AC.x > 0 ? __expf(MC0.x) : 0.f;                                  \
      e0[1] = AC.x > 0 ? __expf(MC0.y) : 0.f;                                  \
      e0[2] = AC.x > 0 ? __expf(MC0.z) : 0.f;                                  \
      e0[3] = AC.x > 0 ? __expf(MC0.w) : 0.f;                                  \
      e1[0] = AC.y > 0 ? __expf(MC1.x) : 0.f;                                  \
      e1[1] = AC.y > 0 ? __expf(MC1.y) : 0.f;                                  \
      e1[2] = AC.y > 0 ? __expf(MC1.z) : 0.f;                                  \
      e1[3] = AC.y > 0 ? __expf(MC1.w) : 0.f;                                  \
      _Pragma("unroll")                                                        \
      for (int i = 0; i < 4; ++i) {                                            \
        const int h2 = (p_h4 * 4 + i) ^ p_q;                                   \
        *(float2*)&Esh[BUF][p_oct][p_q][h2][p_jp * 2] =                        \
            make_float2(e0[i], e1[i]);                                         \
      }                                                                        \
    }                                                                          \
    if ((RD) < 15) { /* prefetch next round's msg/adj; flies across barrier */ \
      const int kg = p_oct * 128 + ((RD) + 1) * 8 + p_jp * 2;                  \
      MN0 = *(const float4*)(mrow + (size_t)kg * Hh);                          \
      MN1 = *(const float4*)(mrow + (size_t)(kg + 1) * Hh);                    \
      AN = *(const int2*)(arow + kg);                                          \
    }                                                                          \
    asm volatile("s_waitcnt lgkmcnt(0)" ::: "memory"); /* publish E writes */  \
    __builtin_amdgcn_s_barrier();                                              \
    __builtin_amdgcn_s_setprio(1);                                             \
    _Pragma("unroll")                                                          \
    for (int kh = 0; kh < 2; ++kh) {                                           \
      _Pragma("unroll")                                                        \
      for (int qi = 0; qi < 4; ++qi) {                                         \
        const int ql = qh * 4 + qi;                                            \
        const float4 e4 = *(const float4*)&Esh[BUF][oct][ql][h ^ ql][kh * 4];  \
        s[qi] += e4.x + e4.y + e4.z + e4.w;                                    \
        r[qi] = fmaf(e4.x, e4.x, fmaf(e4.y, e4.y,                              \
                fmaf(e4.z, e4.z, fmaf(e4.w, e4.w, r[qi]))));                   \
        o[qi].x = fmaf(e4.x, p4[kh * 4 + 0].x, o[qi].x);                       \
        o[qi].y = fmaf(e4.x, p4[kh * 4 + 0].y, o[qi].y);                       \
        o[qi].z = fmaf(e4.x, p4[kh * 4 + 0].z, o[qi].z);                       \
        o[qi].w = fmaf(e4.x, p4[kh * 4 + 0].w, o[qi].w);                       \
        o[qi].x = fmaf(e4.y, p4[kh * 4 + 1].x, o[qi].x);                       \
        o[qi].y = fmaf(e4.y, p4[kh * 4 + 1].y, o[qi].y);                       \
        o[qi].z = fmaf(e4.y, p4[kh * 4 + 1].z, o[qi].z);                       \
        o[qi].w = fmaf(e4.y, p4[kh * 4 + 1].w, o[qi].w);                       \
        o[qi].x = fmaf(e4.z, p4[kh * 4 + 2].x, o[qi].x);                       \
        o[qi].y = fmaf(e4.z, p4[kh * 4 + 2].y, o[qi].y);                       \
        o[qi].z = fmaf(e4.z, p4[kh * 4 + 2].z, o[qi].z);                       \
        o[qi].w = fmaf(e4.z, p4[kh * 4 + 2].w, o[qi].w);                       \
        o[qi].x = fmaf(e4.w, p4[kh * 4 + 3].x, o[qi].x);                       \
        o[qi].y = fmaf(e4.w, p4[kh * 4 + 3].y, o[qi].y);                       \
        o[qi].z = fmaf(e4.w, p4[kh * 4 + 3].z, o[qi].z);                       \
        o[qi].w = fmaf(e4.w, p4[kh * 4 + 3].w, o[qi].w);                       \
      }                                                                        \
    }                                                                          \
    __builtin_amdgcn_s_setprio(0);                                             \
  }

  for (int rr = 0; rr < 8; ++rr) {
    const int rdE = rr * 2;
    ATTN_ROUND(rdE,     0, mA0, mA1, aA, mB0, mB1, aB);
    ATTN_ROUND(rdE + 1, 1, mB0, mB1, aB, mA0, mA1, aA);
  }
#undef ATTN_ROUND

  // ---- epilogue: tree-reduce partial (o,s,r) over the 4 k-quarters ----
  float*  base = &Esh[0][0][0][0][0];
  float4* Ro = (float4*)base;     // 16 KB (1024 float4)
  float*  Rs = base + 4096;       // 256 floats
  float*  Rr = base + 4352;       // 256 floats

  __syncthreads();
  if (w >= 4) {  // oct 2,3 write regions 0..3
    const int reg = w - 4;
#pragma unroll
    for (int qi = 0; qi < 4; ++qi) {
      Ro[(reg * 4 + qi) * 64 + lane] = o[qi];
      if (d4 == 0) {
        Rs[(reg * 4 + qi) * 16 + h] = s[qi];
        Rr[(reg * 4 + qi) * 16 + h] = r[qi];
      }
    }
  }
  __syncthreads();
  if (w < 4) {
#pragma unroll
    for (int qi = 0; qi < 4; ++qi) {
      const float4 v = Ro[(w * 4 + qi) * 64 + lane];
      o[qi].x += v.x; o[qi].y += v.y; o[qi].z += v.z; o[qi].w += v.w;
      s[qi] += Rs[(w * 4 + qi) * 16 + h];
      r[qi] += Rr[(w * 4 + qi) * 16 + h];
    }
  }
  __syncthreads();
  if (w == 2 || w == 3) {  // oct 1 writes regions 0,1
    const int reg = w - 2;
#pragma unroll
    for (int qi = 0; qi < 4; ++qi) {
      Ro[(reg * 4 + qi) * 64 + lane] = o[qi];
      if (d4 == 0) {
        Rs[(reg * 4 + qi) * 16 + h] = s[qi];
        Rr[(reg * 4 + qi) * 16 + h] = r[qi];
      }
    }
  }
  __syncthreads();
  if (w < 2) {
#pragma unroll
    for (int qi = 0; qi < 4; ++qi) {
      const float4 v = Ro[(w * 4 + qi) * 64 + lane];
      o[qi].x += v.x; o[qi].y += v.y; o[qi].z += v.z; o[qi].w += v.w;
      const float st = s[qi] + Rs[(w * 4 + qi) * 16 + h];
      const float rt = r[qi] + Rr[(w * 4 + qi) * 16 + h];
      const float wgt = sqrtf(rt) / (st * st);
      float4 u;
      u.x = o[qi].x * wgt; u.y = o[qi].y * wgt;
      u.z = o[qi].z * wgt; u.w = o[qi].w * wgt;
      const int q = q0 + w * 4 + qi;
      *(float4*)(attn_out + (size_t)(b * NQ + q) * Dd + col) = u;
    }
  }
}

extern "C" void kernel_launch(void* const* d_in, const int* in_sizes, int n_in,
                              void* d_out, int out_size, void* d_ws, size_t ws_size,
                              hipStream_t stream) {
  const float* v_inv    = (const float*)d_in[0];
  const float* messages = (const float*)d_in[1];
  const int*   adj      = (const int*)d_in[2];
  const float* W_in     = (const float*)d_in[3];
  const float* b_in     = (const float*)d_in[4];
  const float* W_out    = (const float*)d_in[5];
  const float* b_out    = (const float*)d_in[6];
  float* out = (float*)d_out;

  float* proj = (float*)d_ws;                      // 4 MB [B,NKV,D]
  float* attn = proj + (size_t)8 * NKV * Dd;       // 4 MB [B,NQ,D]

  dim3 gg(64, 4);
  gemm_bias<<<gg, 256, 0, stream>>>(v_inv, W_in, b_in, proj);
  attn_fused<<<dim3(64, 8), 512, 0, stream>>>(messages, adj, proj, attn);
  gemm_bias<<<gg, 256, 0, stream>>>(attn, W_out, b_out, out);
}

// Round 3
// 385.582 us; speedup vs baseline: 1.0875x; 1.0875x over previous
//
#include <hip/hip_runtime.h>

constexpr int NQ = 512;
constexpr int NKV = 512;
constexpr int Hh = 16;
constexpr int Dd = 256;

// C = A @ W^T + bias. M=4096, N=256, K=256. BM=BN=64, BK=64.
// Next K-tile reg-prefetched after the publish barrier (1 block/CU -> no
// cross-block cover; in-block pipelining is the only latency hiding).
__global__ __launch_bounds__(256) void gemm_bias(
    const float* __restrict__ A, const float* __restrict__ W,
    const float* __restrict__ bias, float* __restrict__ C) {
  __shared__ float As[64][68];
  __shared__ float Ws[64][68];
  const int t = threadIdx.x;
  const int tx = t & 15, ty = t >> 4;
  const int m0 = blockIdx.x * 64, n0 = blockIdx.y * 64;

  float acc[4][4] = {};
  float4 av[4], wv[4];

#pragma unroll
  for (int i = 0; i < 4; ++i) {
    const int flat = i * 256 + t;
    const int r = flat >> 4, c4 = (flat & 15) << 2;
    av[i] = *(const float4*)(A + (size_t)(m0 + r) * 256 + c4);
    wv[i] = *(const float4*)(W + (size_t)(n0 + r) * 256 + c4);
  }

  for (int kb = 0; kb < 4; ++kb) {
#pragma unroll
    for (int i = 0; i < 4; ++i) {
      const int flat = i * 256 + t;
      const int r = flat >> 4, c4 = (flat & 15) << 2;
      As[c4 + 0][r] = av[i].x; As[c4 + 1][r] = av[i].y;
      As[c4 + 2][r] = av[i].z; As[c4 + 3][r] = av[i].w;
      Ws[c4 + 0][r] = wv[i].x; Ws[c4 + 1][r] = wv[i].y;
      Ws[c4 + 2][r] = wv[i].z; Ws[c4 + 3][r] = wv[i].w;
    }
    __syncthreads();
    if (kb < 3) {
#pragma unroll
      for (int i = 0; i < 4; ++i) {
        const int flat = i * 256 + t;
        const int r = flat >> 4, c4 = (flat & 15) << 2;
        av[i] = *(const float4*)(A + (size_t)(m0 + r) * 256 + (kb + 1) * 64 + c4);
        wv[i] = *(const float4*)(W + (size_t)(n0 + r) * 256 + (kb + 1) * 64 + c4);
      }
    }
#pragma unroll 16
    for (int k = 0; k < 64; ++k) {
      float a_[4], w_[4];
      *(float4*)a_ = *(const float4*)&As[k][ty << 2];
      *(float4*)w_ = *(const float4*)&Ws[k][tx << 2];
#pragma unroll
      for (int i = 0; i < 4; ++i)
#pragma unroll
        for (int j = 0; j < 4; ++j)
          acc[i][j] = fmaf(a_[i], w_[j], acc[i][j]);
    }
    if (kb < 3) __syncthreads();
  }

  const float4 bv = *(const float4*)(bias + n0 + (tx << 2));
  const float bb[4] = {bv.x, bv.y, bv.z, bv.w};
#pragma unroll
  for (int i = 0; i < 4; ++i) {
    float4 cv;
    cv.x = acc[i][0] + bb[0]; cv.y = acc[i][1] + bb[1];
    cv.z = acc[i][2] + bb[2]; cv.w = acc[i][3] + bb[3];
    *(float4*)(C + (size_t)(m0 + (ty << 2) + i) * 256 + n0 + (tx << 2)) = cv;
  }
}

// Fused masked softmax + per-head aggregation + L2 rescale.
// v4 = v3 structure (P straight to registers, E double-buffered in LDS,
// ONE raw s_barrier per round publishing only lgkmcnt) with the spill
// fixed: amdgpu_waves_per_eu(4,4) pins the allocator to the 128-VGPR /
// 2-blocks-per-CU tier (v3's allocator chose the 64-reg tier and spilled
// the P tile -> 396 MB scratch writes), and P is loaded as two NAMED
// half-tiles (pa* pre-barrier, pb* post-barrier) so peak live regs ~100.
// Race audit unchanged from v3 (passed): E writes buf[rd&1] pre-barrier(rd);
// readers run between barrier(rd) and barrier(rd+1); next writer of that
// buf is after barrier(rd+1).
__global__ __launch_bounds__(512)
__attribute__((amdgpu_waves_per_eu(4, 4))) void attn_fused(
    const float* __restrict__ msg, const int* __restrict__ adj,
    const float* __restrict__ proj, float* __restrict__ attn_out) {
  __shared__ float Esh[2][4][8][16][12];  // 48 KB: [buf][oct][q][h^q][k(8 used)]

  const int t    = threadIdx.x;
  const int lane = t & 63;
  const int w    = t >> 6;      // wave 0..7
  const int oct  = w >> 1;      // k-quarter for FMA
  const int qh   = w & 1;       // q-half for FMA
  const int h    = lane >> 2;
  const int d4   = lane & 3;
  const int col  = lane << 2;   // = h*16 + d4*4
  const int q0   = blockIdx.x * 8;
  const int b    = blockIdx.y;

  // E-production decomposition
  const int p_h4  = t & 3;
  const int p_q   = (t >> 2) & 7;
  const int p_oct = (t >> 5) & 3;
  const int p_jp  = t >> 7;     // 0..3 (k-pair)

  const float* mrow  = msg + ((size_t)(b * NQ + q0 + p_q) * NKV) * Hh + p_h4 * 4;
  const int*   arow  = adj + (size_t)(b * NQ + q0 + p_q) * NKV;
  const float* pbase = proj + (size_t)b * NKV * Dd;

  float4 o[4] = {};
  float s[4] = {}, r[4] = {};

  float4 mA0, mA1, mB0, mB1;
  int2 aA, aB;
  {  // prologue: round-0 messages
    const int kg = p_oct * 128 + p_jp * 2;
    mA0 = *(const float4*)(mrow + (size_t)kg * Hh);
    mA1 = *(const float4*)(mrow + (size_t)(kg + 1) * Hh);
    aA = *(const int2*)(arow + kg);
  }

// 16 o-FMAs + s/r update for one (kh, qi-sweep) using 4 named P regs.
#define FMA_BLOCK(BUF, KH, P0, P1, P2, P3)                                     \
    _Pragma("unroll")                                                          \
    for (int qi = 0; qi < 4; ++qi) {                                           \
      const int ql = qh * 4 + qi;                                              \
      const float4 e4 = *(const float4*)&Esh[BUF][oct][ql][h ^ ql][(KH) * 4];  \
      s[qi] += e4.x + e4.y + e4.z + e4.w;                                      \
      r[qi] = fmaf(e4.x, e4.x, fmaf(e4.y, e4.y,                                \
              fmaf(e4.z, e4.z, fmaf(e4.w, e4.w, r[qi]))));                     \
      o[qi].x = fmaf(e4.x, P0.x, o[qi].x);                                     \
      o[qi].y = fmaf(e4.x, P0.y, o[qi].y);                                     \
      o[qi].z = fmaf(e4.x, P0.z, o[qi].z);                                     \
      o[qi].w = fmaf(e4.x, P0.w, o[qi].w);                                     \
      o[qi].x = fmaf(e4.y, P1.x, o[qi].x);                                     \
      o[qi].y = fmaf(e4.y, P1.y, o[qi].y);                                     \
      o[qi].z = fmaf(e4.y, P1.z, o[qi].z);                                     \
      o[qi].w = fmaf(e4.y, P1.w, o[qi].w);                                     \
      o[qi].x = fmaf(e4.z, P2.x, o[qi].x);                                     \
      o[qi].y = fmaf(e4.z, P2.y, o[qi].y);                                     \
      o[qi].z = fmaf(e4.z, P2.z, o[qi].z);                                     \
      o[qi].w = fmaf(e4.z, P2.w, o[qi].w);                                     \
      o[qi].x = fmaf(e4.w, P3.x, o[qi].x);                                     \
      o[qi].y = fmaf(e4.w, P3.y, o[qi].y);                                     \
      o[qi].z = fmaf(e4.w, P3.z, o[qi].z);                                     \
      o[qi].w = fmaf(e4.w, P3.w, o[qi].w);                                     \
    }

#define ATTN_ROUND(RD, BUF, MC0, MC1, AC, MN0, MN1, AN)                        \
  {                                                                            \
    const float* prow = pbase + (size_t)(oct * 128 + (RD) * 8) * Dd + col;     \
    /* first P half-tile: issued pre-barrier, flies across it (raw barrier  */ \
    /* waits lgkmcnt only); consumed by kh=0 FMA.                           */ \
    const float4 pa0 = *(const float4*)(prow + 0 * Dd);                        \
    const float4 pa1 = *(const float4*)(prow + 1 * Dd);                        \
    const float4 pa2 = *(const float4*)(prow + 2 * Dd);                        \
    const float4 pa3 = *(const float4*)(prow + 3 * Dd);                        \
    {                                                                          \
      float e0[4], e1[4];                                                      \
      e0[0] = AC.x > 0 ? __expf(MC0.x) : 0.f;                                  \
      e0[1] = AC.x > 0 ? __expf(MC0.y) : 0.f;                                  \
      e0[2] = AC.x > 0 ? __expf(MC0.z) : 0.f;                                  \
      e0[3] = AC.x > 0 ? __expf(MC0.w) : 0.f;                                  \
      e1[0] = AC.y > 0 ? __expf(MC1.x) : 0.f;                                  \
      e1[1] = AC.y > 0 ? __expf(MC1.y) : 0.f;                                  \
      e1[2] = AC.y > 0 ? __expf(MC1.z) : 0.f;                                  \
      e1[3] = AC.y > 0 ? __expf(MC1.w) : 0.f;                                  \
      _Pragma("unroll")                                                        \
      for (int i = 0; i < 4; ++i) {                                            \
        const int h2 = (p_h4 * 4 + i) ^ p_q;                                   \
        *(float2*)&Esh[BUF][p_oct][p_q][h2][p_jp * 2] =                        \
            make_float2(e0[i], e1[i]);                                         \
      }                                                                        \
    }                                                                          \
    asm volatile("s_waitcnt lgkmcnt(0)" ::: "memory"); /* publish E writes */  \
    __builtin_amdgcn_s_barrier();                                              \
    /* second P half-tile first (so its completion wait doesn't chain on   */  \
    /* the slower HBM msg prefetch), then next-round msg/adj prefetch.     */  \
    const float4 pb0 = *(const float4*)(prow + 4 * Dd);                        \
    const float4 pb1 = *(const float4*)(prow + 5 * Dd);                        \
    const float4 pb2 = *(const float4*)(prow + 6 * Dd);                        \
    const float4 pb3 = *(const float4*)(prow + 7 * Dd);                        \
    if ((RD) < 15) {                                                           \
      const int kg = p_oct * 128 + ((RD) + 1) * 8 + p_jp * 2;                  \
      MN0 = *(const float4*)(mrow + (size_t)kg * Hh);                          \
      MN1 = *(const float4*)(mrow + (size_t)(kg + 1) * Hh);                    \
      AN = *(const int2*)(arow + kg);                                          \
    }                                                                          \
    __builtin_amdgcn_s_setprio(1);                                             \
    FMA_BLOCK(BUF, 0, pa0, pa1, pa2, pa3)                                      \
    FMA_BLOCK(BUF, 1, pb0, pb1, pb2, pb3)                                      \
    __builtin_amdgcn_s_setprio(0);                                             \
  }

  for (int rr = 0; rr < 8; ++rr) {
    const int rdE = rr * 2;
    ATTN_ROUND(rdE,     0, mA0, mA1, aA, mB0, mB1, aB);
    ATTN_ROUND(rdE + 1, 1, mB0, mB1, aB, mA0, mA1, aA);
  }
#undef ATTN_ROUND
#undef FMA_BLOCK

  // ---- epilogue: tree-reduce partial (o,s,r) over the 4 k-quarters ----
  float*  base = &Esh[0][0][0][0][0];
  float4* Ro = (float4*)base;     // 16 KB (1024 float4)
  float*  Rs = base + 4096;       // 256 floats
  float*  Rr = base + 4352;       // 256 floats

  __syncthreads();
  if (w >= 4) {  // oct 2,3 write regions 0..3
    const int reg = w - 4;
#pragma unroll
    for (int qi = 0; qi < 4; ++qi) {
      Ro[(reg * 4 + qi) * 64 + lane] = o[qi];
      if (d4 == 0) {
        Rs[(reg * 4 + qi) * 16 + h] = s[qi];
        Rr[(reg * 4 + qi) * 16 + h] = r[qi];
      }
    }
  }
  __syncthreads();
  if (w < 4) {
#pragma unroll
    for (int qi = 0; qi < 4; ++qi) {
      const float4 v = Ro[(w * 4 + qi) * 64 + lane];
      o[qi].x += v.x; o[qi].y += v.y; o[qi].z += v.z; o[qi].w += v.w;
      s[qi] += Rs[(w * 4 + qi) * 16 + h];
      r[qi] += Rr[(w * 4 + qi) * 16 + h];
    }
  }
  __syncthreads();
  if (w == 2 || w == 3) {  // oct 1 writes regions 0,1
    const int reg = w - 2;
#pragma unroll
    for (int qi = 0; qi < 4; ++qi) {
      Ro[(reg * 4 + qi) * 64 + lane] = o[qi];
      if (d4 == 0) {
        Rs[(reg * 4 + qi) * 16 + h] = s[qi];
        Rr[(reg * 4 + qi) * 16 + h] = r[qi];
      }
    }
  }
  __syncthreads();
  if (w < 2) {
#pragma unroll
    for (int qi = 0; qi < 4; ++qi) {
      const float4 v = Ro[(w * 4 + qi) * 64 + lane];
      o[qi].x += v.x; o[qi].y += v.y; o[qi].z += v.z; o[qi].w += v.w;
      const float st = s[qi] + Rs[(w * 4 + qi) * 16 + h];
      const float rt = r[qi] + Rr[(w * 4 + qi) * 16 + h];
      const float wgt = sqrtf(rt) / (st * st);
      float4 u;
      u.x = o[qi].x * wgt; u.y = o[qi].y * wgt;
      u.z = o[qi].z * wgt; u.w = o[qi].w * wgt;
      const int q = q0 + w * 4 + qi;
      *(float4*)(attn_out + (size_t)(b * NQ + q) * Dd + col) = u;
    }
  }
}

extern "C" void kernel_launch(void* const* d_in, const int* in_sizes, int n_in,
                              void* d_out, int out_size, void* d_ws, size_t ws_size,
                              hipStream_t stream) {
  const float* v_inv    = (const float*)d_in[0];
  const float* messages = (const float*)d_in[1];
  const int*   adj      = (const int*)d_in[2];
  const float* W_in     = (const float*)d_in[3];
  const float* b_in     = (const float*)d_in[4];
  const float* W_out    = (const float*)d_in[5];
  const float* b_out    = (const float*)d_in[6];
  float* out = (float*)d_out;

  float* proj = (float*)d_ws;                      // 4 MB [B,NKV,D]
  float* attn = proj + (size_t)8 * NKV * Dd;       // 4 MB [B,NQ,D]

  dim3 gg(64, 4);
  gemm_bias<<<gg, 256, 0, stream>>>(v_inv, W_in, b_in, proj);
  attn_fused<<<dim3(64, 8), 512, 0, stream>>>(messages, adj, proj, attn);
  gemm_bias<<<gg, 256, 0, stream>>>(attn, W_out, b_out, out);
}

// Round 4
// 326.389 us; speedup vs baseline: 1.2847x; 1.1814x over previous
//
#include <hip/hip_runtime.h>

constexpr int NQ = 512;
constexpr int NKV = 512;
constexpr int Hh = 16;
constexpr int Dd = 256;

// C = A @ W^T + bias. M=4096, N=256, K=256. BM=BN=64, BK=64.
__global__ __launch_bounds__(256) void gemm_bias(
    const float* __restrict__ A, const float* __restrict__ W,
    const float* __restrict__ bias, float* __restrict__ C) {
  __shared__ float As[64][68];
  __shared__ float Ws[64][68];
  const int t = threadIdx.x;
  const int tx = t & 15, ty = t >> 4;
  const int m0 = blockIdx.x * 64, n0 = blockIdx.y * 64;

  float acc[4][4] = {};
  float4 av[4], wv[4];

#pragma unroll
  for (int i = 0; i < 4; ++i) {
    const int flat = i * 256 + t;
    const int r = flat >> 4, c4 = (flat & 15) << 2;
    av[i] = *(const float4*)(A + (size_t)(m0 + r) * 256 + c4);
    wv[i] = *(const float4*)(W + (size_t)(n0 + r) * 256 + c4);
  }

  for (int kb = 0; kb < 4; ++kb) {
#pragma unroll
    for (int i = 0; i < 4; ++i) {
      const int flat = i * 256 + t;
      const int r = flat >> 4, c4 = (flat & 15) << 2;
      As[c4 + 0][r] = av[i].x; As[c4 + 1][r] = av[i].y;
      As[c4 + 2][r] = av[i].z; As[c4 + 3][r] = av[i].w;
      Ws[c4 + 0][r] = wv[i].x; Ws[c4 + 1][r] = wv[i].y;
      Ws[c4 + 2][r] = wv[i].z; Ws[c4 + 3][r] = wv[i].w;
    }
    __syncthreads();
    if (kb < 3) {
#pragma unroll
      for (int i = 0; i < 4; ++i) {
        const int flat = i * 256 + t;
        const int r = flat >> 4, c4 = (flat & 15) << 2;
        av[i] = *(const float4*)(A + (size_t)(m0 + r) * 256 + (kb + 1) * 64 + c4);
        wv[i] = *(const float4*)(W + (size_t)(n0 + r) * 256 + (kb + 1) * 64 + c4);
      }
    }
#pragma unroll 16
    for (int k = 0; k < 64; ++k) {
      float a_[4], w_[4];
      *(float4*)a_ = *(const float4*)&As[k][ty << 2];
      *(float4*)w_ = *(const float4*)&Ws[k][tx << 2];
#pragma unroll
      for (int i = 0; i < 4; ++i)
#pragma unroll
        for (int j = 0; j < 4; ++j)
          acc[i][j] = fmaf(a_[i], w_[j], acc[i][j]);
    }
    if (kb < 3) __syncthreads();
  }

  const float4 bv = *(const float4*)(bias + n0 + (tx << 2));
  const float bb[4] = {bv.x, bv.y, bv.z, bv.w};
#pragma unroll
  for (int i = 0; i < 4; ++i) {
    float4 cv;
    cv.x = acc[i][0] + bb[0]; cv.y = acc[i][1] + bb[1];
    cv.z = acc[i][2] + bb[2]; cv.w = acc[i][3] + bb[3];
    *(float4*)(C + (size_t)(m0 + (ty << 2) + i) * 256 + n0 + (tx << 2)) = cv;
  }
}

// Fused masked softmax + per-head aggregation + L2 rescale. v5:
// P staged one round ahead via global_load_lds into a SINGLE 32KB LDS tile
// (zero P registers -> fits the allocator's 64-VGPR tier, no spill; v3/v4's
// reg-held P spilled ~320MB scratch). E double-buffered (48KB). Per round:
//   1. issue msg(rd+1) prefetch (top of round: ~600cyc before use)
//   2. E-compute(rd) -> Esh[rd&1]            (compiler auto-waits msg(rd))
//   3. s_waitcnt vmcnt(3): P-dma(rd) complete, msg(rd+1) stays in flight
//   4. lgkmcnt(0); raw s_barrier; sched_barrier(0)   <- E+P published
//   5. setprio(1); FMA from Psh + Esh[rd&1]; setprio(0)
//   6. __syncthreads()   <- Psh WAR fence (vmcnt drain ~free: only msg left)
//   7. issue P-dma(rd+1)
// VMEM order audit: msg(rd)[3] < P(rd)[4] < msg(rd+1)[3] -> vmcnt(3) at
// step 3 retires exactly through P(rd). LDS 80KB -> 2 blocks/CU.
__global__ __launch_bounds__(512, 4) void attn_fused(
    const float* __restrict__ msg, const int* __restrict__ adj,
    const float* __restrict__ proj, float* __restrict__ attn_out) {
  __shared__ float Psh[4][8][256];        // 32 KB: [oct][k][col], linear (DMA dest)
  __shared__ float Esh[2][4][8][16][12];  // 48 KB: [buf][oct][q][h^q][k(8 used)]

  const int t    = threadIdx.x;
  const int lane = t & 63;
  const int w    = t >> 6;      // wave 0..7
  const int oct  = w >> 1;      // k-quarter for FMA
  const int qh   = w & 1;       // q-half for FMA
  const int h    = lane >> 2;
  const int d4   = lane & 3;
  const int col  = lane << 2;   // = h*16 + d4*4
  const int q0   = blockIdx.x * 8;
  const int b    = blockIdx.y;

  // E-production decomposition
  const int p_h4  = t & 3;
  const int p_q   = (t >> 2) & 7;
  const int p_oct = (t >> 5) & 3;
  const int p_jp  = t >> 7;     // 0..3 (k-pair)

  const float* mrow  = msg + ((size_t)(b * NQ + q0 + p_q) * NKV) * Hh + p_h4 * 4;
  const int*   arow  = adj + (size_t)(b * NQ + q0 + p_q) * NKV;
  const float* pbase = proj + (size_t)b * NKV * Dd;

  float4 o[4] = {};
  float s[4] = {}, r[4] = {};

  float4 mA0, mA1, mB0, mB1;
  int2 aA, aB;

#define STAGE_P(RD)                                                            \
  _Pragma("unroll")                                                            \
  for (int i = 0; i < 4; ++i) {                                                \
    const float* g = pbase + (size_t)(i * 128 + (RD) * 8 + w) * Dd + (lane << 2); \
    __builtin_amdgcn_global_load_lds(                                          \
        (const __attribute__((address_space(1))) unsigned int*)g,              \
        (__attribute__((address_space(3))) unsigned int*)&Psh[i][w][0],        \
        16, 0, 0);                                                             \
  }

  {  // prologue: round-0 messages, then round-0 P DMA
    const int kg = p_oct * 128 + p_jp * 2;
    mA0 = *(const float4*)(mrow + (size_t)kg * Hh);
    mA1 = *(const float4*)(mrow + (size_t)(kg + 1) * Hh);
    aA = *(const int2*)(arow + kg);
    STAGE_P(0)
  }

#define FMA_BLOCK(BUF, KH)                                                     \
  {                                                                            \
    const float4 p0 = *(const float4*)&Psh[oct][(KH) * 4 + 0][col];            \
    const float4 p1 = *(const float4*)&Psh[oct][(KH) * 4 + 1][col];            \
    const float4 p2 = *(const float4*)&Psh[oct][(KH) * 4 + 2][col];            \
    const float4 p3 = *(const float4*)&Psh[oct][(KH) * 4 + 3][col];            \
    _Pragma("unroll")                                                          \
    for (int qi = 0; qi < 4; ++qi) {                                           \
      const int ql = qh * 4 + qi;                                              \
      const float4 e4 = *(const float4*)&Esh[BUF][oct][ql][h ^ ql][(KH) * 4];  \
      s[qi] += e4.x + e4.y + e4.z + e4.w;                                      \
      r[qi] = fmaf(e4.x, e4.x, fmaf(e4.y, e4.y,                                \
              fmaf(e4.z, e4.z, fmaf(e4.w, e4.w, r[qi]))));                     \
      o[qi].x = fmaf(e4.x, p0.x, o[qi].x);                                     \
      o[qi].y = fmaf(e4.x, p0.y, o[qi].y);                                     \
      o[qi].z = fmaf(e4.x, p0.z, o[qi].z);                                     \
      o[qi].w = fmaf(e4.x, p0.w, o[qi].w);                                     \
      o[qi].x = fmaf(e4.y, p1.x, o[qi].x);                                     \
      o[qi].y = fmaf(e4.y, p1.y, o[qi].y);                                     \
      o[qi].z = fmaf(e4.y, p1.z, o[qi].z);                                     \
      o[qi].w = fmaf(e4.y, p1.w, o[qi].w);                                     \
      o[qi].x = fmaf(e4.z, p2.x, o[qi].x);                                     \
      o[qi].y = fmaf(e4.z, p2.y, o[qi].y);                                     \
      o[qi].z = fmaf(e4.z, p2.z, o[qi].z);                                     \
      o[qi].w = fmaf(e4.z, p2.w, o[qi].w);                                     \
      o[qi].x = fmaf(e4.w, p3.x, o[qi].x);                                     \
      o[qi].y = fmaf(e4.w, p3.y, o[qi].y);                                     \
      o[qi].z = fmaf(e4.w, p3.z, o[qi].z);                                     \
      o[qi].w = fmaf(e4.w, p3.w, o[qi].w);                                     \
    }                                                                          \
  }

#define ATTN_ROUND(RD, BUF, MC0, MC1, AC, MN0, MN1, AN)                        \
  {                                                                            \
    if ((RD) < 15) { /* next-round msg prefetch, ~600cyc ahead of use */       \
      const int kg = p_oct * 128 + ((RD) + 1) * 8 + p_jp * 2;                  \
      MN0 = *(const float4*)(mrow + (size_t)kg * Hh);                          \
      MN1 = *(const float4*)(mrow + (size_t)(kg + 1) * Hh);                    \
      AN = *(const int2*)(arow + kg);                                          \
    }                                                                          \
    {                                                                          \
      float e0[4], e1[4];                                                      \
      e0[0] = AC.x > 0 ? __expf(MC0.x) : 0.f;                                  \
      e0[1] = AC.x > 0 ? __expf(MC0.y) : 0.f;                                  \
      e0[2] = AC.x > 0 ? __expf(MC0.z) : 0.f;                                  \
      e0[3] = AC.x > 0 ? __expf(MC0.w) : 0.f;                                  \
      e1[0] = AC.y > 0 ? __expf(MC1.x) : 0.f;                                  \
      e1[1] = AC.y > 0 ? __expf(MC1.y) : 0.f;                                  \
      e1[2] = AC.y > 0 ? __expf(MC1.z) : 0.f;                                  \
      e1[3] = AC.y > 0 ? __expf(MC1.w) : 0.f;                                  \
      _Pragma("unroll")                                                        \
      for (int i = 0; i < 4; ++i) {                                            \
        const int h2 = (p_h4 * 4 + i) ^ p_q;                                   \
        *(float2*)&Esh[BUF][p_oct][p_q][h2][p_jp * 2] =                        \
            make_float2(e0[i], e1[i]);                                         \
      }                                                                        \
    }                                                                          \
    if ((RD) < 15) {                                                           \
      asm volatile("s_waitcnt vmcnt(3)" ::: "memory");  /* P(RD) done */       \
    } else {                                                                   \
      asm volatile("s_waitcnt vmcnt(0)" ::: "memory");                         \
    }                                                                          \
    asm volatile("s_waitcnt lgkmcnt(0)" ::: "memory");  /* publish E */        \
    __builtin_amdgcn_s_barrier();                                              \
    __builtin_amdgcn_sched_barrier(0);                                         \
    __builtin_amdgcn_s_setprio(1);                                             \
    FMA_BLOCK(BUF, 0)                                                          \
    FMA_BLOCK(BUF, 1)                                                          \
    __builtin_amdgcn_s_setprio(0);                                             \
    __syncthreads();  /* Psh WAR fence; only msg loads left in vmcnt */        \
    if ((RD) < 15) { STAGE_P((RD) + 1) }                                       \
  }

  for (int rr = 0; rr < 8; ++rr) {
    const int rdE = rr * 2;
    ATTN_ROUND(rdE,     0, mA0, mA1, aA, mB0, mB1, aB);
    ATTN_ROUND(rdE + 1, 1, mB0, mB1, aB, mA0, mA1, aA);
  }
#undef ATTN_ROUND
#undef FMA_BLOCK
#undef STAGE_P

  // ---- epilogue: tree-reduce partial (o,s,r) over the 4 k-quarters ----
  float*  base = &Esh[0][0][0][0][0];
  float4* Ro = (float4*)base;     // 16 KB (1024 float4)
  float*  Rs = base + 4096;       // 256 floats
  float*  Rr = base + 4352;       // 256 floats

  __syncthreads();
  if (w >= 4) {  // oct 2,3 write regions 0..3
    const int reg = w - 4;
#pragma unroll
    for (int qi = 0; qi < 4; ++qi) {
      Ro[(reg * 4 + qi) * 64 + lane] = o[qi];
      if (d4 == 0) {
        Rs[(reg * 4 + qi) * 16 + h] = s[qi];
        Rr[(reg * 4 + qi) * 16 + h] = r[qi];
      }
    }
  }
  __syncthreads();
  if (w < 4) {
#pragma unroll
    for (int qi = 0; qi < 4; ++qi) {
      const float4 v = Ro[(w * 4 + qi) * 64 + lane];
      o[qi].x += v.x; o[qi].y += v.y; o[qi].z += v.z; o[qi].w += v.w;
      s[qi] += Rs[(w * 4 + qi) * 16 + h];
      r[qi] += Rr[(w * 4 + qi) * 16 + h];
    }
  }
  __syncthreads();
  if (w == 2 || w == 3) {  // oct 1 writes regions 0,1
    const int reg = w - 2;
#pragma unroll
    for (int qi = 0; qi < 4; ++qi) {
      Ro[(reg * 4 + qi) * 64 + lane] = o[qi];
      if (d4 == 0) {
        Rs[(reg * 4 + qi) * 16 + h] = s[qi];
        Rr[(reg * 4 + qi) * 16 + h] = r[qi];
      }
    }
  }
  __syncthreads();
  if (w < 2) {
#pragma unroll
    for (int qi = 0; qi < 4; ++qi) {
      const float4 v = Ro[(w * 4 + qi) * 64 + lane];
      o[qi].x += v.x; o[qi].y += v.y; o[qi].z += v.z; o[qi].w += v.w;
      const float st = s[qi] + Rs[(w * 4 + qi) * 16 + h];
      const float rt = r[qi] + Rr[(w * 4 + qi) * 16 + h];
      const float wgt = sqrtf(rt) / (st * st);
      float4 u;
      u.x = o[qi].x * wgt; u.y = o[qi].y * wgt;
      u.z = o[qi].z * wgt; u.w = o[qi].w * wgt;
      const int q = q0 + w * 4 + qi;
      *(float4*)(attn_out + (size_t)(b * NQ + q) * Dd + col) = u;
    }
  }
}

extern "C" void kernel_launch(void* const* d_in, const int* in_sizes, int n_in,
                              void* d_out, int out_size, void* d_ws, size_t ws_size,
                              hipStream_t stream) {
  const float* v_inv    = (const float*)d_in[0];
  const float* messages = (const float*)d_in[1];
  const int*   adj      = (const int*)d_in[2];
  const float* W_in     = (const float*)d_in[3];
  const float* b_in     = (const float*)d_in[4];
  const float* W_out    = (const float*)d_in[5];
  const float* b_out    = (const float*)d_in[6];
  float* out = (float*)d_out;

  float* proj = (float*)d_ws;                      // 4 MB [B,NKV,D]
  float* attn = proj + (size_t)8 * NKV * Dd;       // 4 MB [B,NQ,D]

  dim3 gg(64, 4);
  gemm_bias<<<gg, 256, 0, stream>>>(v_inv, W_in, b_in, proj);
  attn_fused<<<dim3(64, 8), 512, 0, stream>>>(messages, adj, proj, attn);
  gemm_bias<<<gg, 256, 0, stream>>>(attn, W_out, b_out, out);
}